// Round 12
// baseline (58.340 us; speedup 1.0000x reference)
//
#include <hip/hip_runtime.h>
#include <hip/hip_bf16.h>

// MSA: B=4, S=2048, D=256, H=8, DH=32
// q/k/v = seq @ W[h] + b[h]; out = softmax(q k^T / sqrt(32)) v, heads hstacked -> [B,S,D] f32
//
// proj: LDS-staged GEMM (r10, proven): A 64x256 + B 64x256 staged via coalesced
// global_load_lds (XOR-swizzled via inverse-permuted source), one barrier.
// attn: 3-buffer counted-vmcnt pipeline, phase-interleaved staging (one
// global_load_lds issue per 32-key subtile phase, m201-style), vmcnt(4) BEFORE
// the barrier (each wave drains own loads; barrier unions the guarantee).
// l in f32 VALU adds (matrix pipe is the floor; VALU has slack). Even/odd
// acc chains. Zero-shuffle P via even/odd-interleaved K rows; no max tracking.

#define NB 4
#define NS 2048
#define ND 256
#define NH 8
#define NDH 32
#define KT 128           // keys per staged macro-tile (4 x 32-key sub-tiles)
#define NT (NS / KT)     // 16 tiles

typedef __attribute__((ext_vector_type(8))) short short8;
typedef __attribute__((ext_vector_type(4))) float float4v;

static __device__ __forceinline__ unsigned short f2bf(float f) {
    union { float f; unsigned int u; } v; v.f = f;
    unsigned int r = (v.u + 0x7FFFu + ((v.u >> 16) & 1u)) >> 16;
    return (unsigned short)r;
}

static __device__ __forceinline__ unsigned int pk2bf(float lo, float hi) {
    __hip_bfloat162 h = __float22bfloat162_rn(float2{lo, hi});  // x=lo -> low 16 bits
    union { __hip_bfloat162 h; unsigned int u; } c; c.h = h;
    return c.u;
}

#if defined(__has_builtin)
#if __has_builtin(__builtin_amdgcn_exp2f)
#define EXP2F(x) __builtin_amdgcn_exp2f(x)
#endif
#endif
#ifndef EXP2F
#define EXP2F(x) exp2f(x)
#endif

// XOR-swizzle within a 2KB region (128B rows): spread 16B slots across banks.
#define SWZ(x) ((x) ^ ((((x) >> 7) & 7) << 4))

// ---------------- fused prep: seq f32->bf16 (blocks 0..2047), W transpose (2048..2815) ----------------
__global__ __launch_bounds__(256) void prep(const float* __restrict__ seq,
                                            unsigned short* __restrict__ seqb,
                                            const float* __restrict__ Wq,
                                            const float* __restrict__ Wk,
                                            const float* __restrict__ Wv,
                                            unsigned short* __restrict__ Wt) {
    int bx = (int)blockIdx.x;
    if (bx < 2048) {
        int i = (bx * 256 + (int)threadIdx.x) * 4;  // 2M elems / 4
        float4 v = *(const float4*)(seq + i);
        ushort4 o;
        o.x = f2bf(v.x); o.y = f2bf(v.y); o.z = f2bf(v.z); o.w = f2bf(v.w);
        *(ushort4*)(seqb + i) = o;
    } else {
        int idx = (bx - 2048) * 256 + (int)threadIdx.x;  // 768*256
        int c = idx >> 8, d = idx & 255;
        int mat = c >> 8;
        int cm = c & 255;
        int h = cm >> 5, e = cm & 31;
        const float* W = (mat == 0) ? Wq : (mat == 1) ? Wk : Wv;
        Wt[c * 256 + d] = f2bf(W[(h * 256 + d) * 32 + e]);
    }
}

// ---------------- projection GEMM: M=8192, N=768, K=256, LDS-staged ----------------
__global__ __launch_bounds__(256, 2) void proj(const unsigned short* __restrict__ seqb,
                                               const unsigned short* __restrict__ Wt,
                                               const float* __restrict__ bq,
                                               const float* __restrict__ bk,
                                               const float* __restrict__ bv,
                                               unsigned short* __restrict__ Q,
                                               unsigned short* __restrict__ K,
                                               unsigned short* __restrict__ Vt) {
    __shared__ __align__(16) unsigned short plds[32768];  // A shorts [0,16384), B [16384,32768)

    int m0 = blockIdx.x * 64;        // 128 m-blocks
    int c0 = blockIdx.y * 64;        // 12 c-blocks (64-col tiles never cross a matrix boundary)
    int tid = (int)threadIdx.x;
    int wave = tid >> 6, lane = tid & 63;
    int g = lane >> 4, r4 = lane & 15;

    // ---- stage A and B tiles: 4096 slots of 16B, 16 per thread ----
#pragma unroll
    for (int j = 0; j < 16; ++j) {
        int s = tid + 256 * j;
        int local = s & 2047;
        int row = local >> 5;
        int col16 = (local & 31) ^ (row & 7);
        const unsigned short* src = (s < 2048)
            ? (seqb + (size_t)(m0 + row) * 256 + col16 * 8)
            : (Wt + (size_t)(c0 + row) * 256 + col16 * 8);
        __builtin_amdgcn_global_load_lds(
            (const __attribute__((address_space(1))) unsigned int*)src,
            (__attribute__((address_space(3))) unsigned int*)(&plds[s * 8]), 16, 0, 0);
    }
    __syncthreads();  // drains vmcnt(0): both tiles resident

    const unsigned short* ldsA = plds;
    const unsigned short* ldsB = plds + 16384;
    int rowA = wave * 16 + r4;
    int xA = r4 & 7;

    float4v acc[4];
#pragma unroll
    for (int ct = 0; ct < 4; ++ct) acc[ct] = (float4v){0.f, 0.f, 0.f, 0.f};

#pragma unroll
    for (int i = 0; i < 8; ++i) {
        int cp = ((4 * i + g) ^ xA) * 8;
        short8 a = *(const short8*)(ldsA + rowA * 256 + cp);
#pragma unroll
        for (int ct = 0; ct < 4; ++ct) {
            short8 b = *(const short8*)(ldsB + (ct * 16 + r4) * 256 + cp);
            acc[ct] = __builtin_amdgcn_mfma_f32_16x16x32_bf16(a, b, acc[ct], 0, 0, 0);
        }
    }

    const float SC = 0.17677669529663687f * 1.4426950408889634f;  // 1/sqrt(32)*log2(e)
#pragma unroll
    for (int ct = 0; ct < 4; ++ct) {
        int c = c0 + ct * 16 + r4;
        int mat = c >> 8;
        int cm = c & 255;
        int h = cm >> 5, e = cm & 31;
        float bias = ((mat == 0) ? bq : (mat == 1) ? bk : bv)[cm];
#pragma unroll
        for (int r = 0; r < 4; ++r) {
            int m = m0 + wave * 16 + 4 * g + r;
            int b = m >> 11, s = m & 2047;
            float val = acc[ct][r] + bias;
            if (mat == 0) {
                Q[((b * NH + h) * NS + s) * NDH + e] = f2bf(val * SC);
            } else if (mat == 1) {
                K[((b * NH + h) * NS + s) * NDH + e] = f2bf(val);
            } else {
                Vt[((b * NH + h) * NDH + e) * NS + s] = f2bf(val);
            }
        }
    }
}

// ---------------- flash attention, 3-buffer, phase-interleaved staging ----------------
// grid: 512 blocks (32 bh x 16 q-tiles of 128), XCD-swizzled. block: 4 waves.
// Wave owns 32 q-rows (two 16-q blocks). 128-key macro tiles (4 x 32-key
// sub-tiles), triple-buffered (3 x 16KB LDS). Each 4KB sub-tile: K 2KB
// [row i = key 2i, row 16+i = key 2i+1][32 dh], V 2KB [dh][32 keys], swizzled.
// Per iter: vmcnt(4) -> barrier -> 4x { STAGE-one-subtile(t+2) ; compute }.
__global__ __launch_bounds__(256, 2) void attn_kernel(const unsigned short* __restrict__ Q,
                                                      const unsigned short* __restrict__ K,
                                                      const unsigned short* __restrict__ Vt,
                                                      float* __restrict__ out) {
    __shared__ __align__(16) unsigned short lds[3][8192];  // 3 x 16KB

    int bx = (int)blockIdx.x;
    int wid = (bx & 7) * 64 + (bx >> 3);   // XCD swizzle (512 % 8 == 0)
    int bh = wid >> 4;
    int qt = wid & 15;
    int tid = (int)threadIdx.x;
    int wave = tid >> 6, lane = tid & 63;
    int g = lane >> 4, r4 = lane & 15;
    int q0 = qt * 128 + wave * 32;

    const unsigned short* Qb = Q + (size_t)bh * NS * NDH;
    const unsigned short* Kb = K + (size_t)bh * NS * NDH;
    const unsigned short* Vb = Vt + (size_t)bh * NDH * NS;

    // ---- staging: thread stages one 16B slot per 32-key sub-tile (4/macro) ----
    const unsigned short* sgp;
    int strideT;         // shorts per 128-key macro-tile
    int strideB;         // shorts per 32-key sub-tile step
    unsigned int sloff;  // dest offset within a buffer, in shorts
    {
        int slot = tid & 127;
        int sL = slot ^ ((slot >> 3) & 7);  // involution (slot-unit form of SWZ)
        int row = sL >> 2, c16 = sL & 3;
        if (tid < 128) {  // K region: row<16 -> key 2*row ; row>=16 -> key 2*(row-16)+1
            int key = (row < 16) ? (2 * row) : (2 * (row - 16) + 1);
            sgp = Kb + key * NDH + c16 * 8;
            strideT = KT * NDH;   // 4096
            strideB = 32 * NDH;   // 1024
            sloff = slot * 8;
        } else {          // V region: row = dh
            sgp = Vb + row * NS + c16 * 8;
            strideT = KT;         // 128
            strideB = 32;
            sloff = 1024 + slot * 8;
        }
    }

// stage one 32-key sub-tile p of macro-tile t into buffer bufi
#define STAGE1(bufi, t, p)                                                                    \
    __builtin_amdgcn_global_load_lds(                                                         \
        (const __attribute__((address_space(1))) unsigned int*)(sgp + (size_t)(t) * strideT + (p) * strideB), \
        (__attribute__((address_space(3))) unsigned int*)(&lds[bufi][sloff + (p) * 2048]), 16, 0, 0)

    // ---- per-lane swizzled read offsets (bytes within a 4KB sub-tile) ----
    int kOff0 = SWZ(r4 * 64 + g * 16);               // K rows 0..15 (even keys)
    int kOff1 = SWZ((16 + r4) * 64 + g * 16);        // K rows 16..31 (odd keys)
    int vOff0 = 2048 + SWZ(r4 * 64 + g * 16);        // V dh 0..15
    int vOff1 = 2048 + SWZ((16 + r4) * 64 + g * 16); // V dh 16..31

    // ---- Q fragments (B operand of QK), pre-scaled by 1/sqrt(32)*log2e ----
    short8 qf0 = *(const short8*)(Qb + (q0 + r4) * NDH + 8 * g);
    short8 qf1 = *(const short8*)(Qb + (q0 + 16 + r4) * NDH + 8 * g);

    // even/odd sub-tile accumulator sets (split serial MFMA chains)
    float4v aA0e = {0,0,0,0}, aB0e = {0,0,0,0}, aA1e = {0,0,0,0}, aB1e = {0,0,0,0};
    float4v aA0o = {0,0,0,0}, aB0o = {0,0,0,0}, aA1o = {0,0,0,0}, aB1o = {0,0,0,0};
    float l0 = 0.f, l1 = 0.f;
    const float4v zero = {0.f, 0.f, 0.f, 0.f};

    auto process = [&](const char* buf, float4v& A0, float4v& B0, float4v& A1, float4v& B1) {
        short8 kf0 = *(const short8*)(buf + kOff0);
        short8 kf1 = *(const short8*)(buf + kOff1);
        short8 va0 = *(const short8*)(buf + vOff0);
        short8 va1 = *(const short8*)(buf + vOff1);
        // q-block 0: scores s0[r]=key 8g+2r, s1[r]=key 8g+2r+1 (q=r4)
        {
            float4v s0 = __builtin_amdgcn_mfma_f32_16x16x32_bf16(kf0, qf0, zero, 0, 0, 0);
            float4v s1 = __builtin_amdgcn_mfma_f32_16x16x32_bf16(kf1, qf0, zero, 0, 0, 0);
            union { short8 s; unsigned int u[4]; } pb;
#pragma unroll
            for (int r = 0; r < 4; ++r) {
                float pe = EXP2F(s0[r]), po = EXP2F(s1[r]);
                l0 += pe + po;
                pb.u[r] = pk2bf(pe, po);  // B-frag k-elems (2r, 2r+1)
            }
            A0 = __builtin_amdgcn_mfma_f32_16x16x32_bf16(va0, pb.s, A0, 0, 0, 0);
            B0 = __builtin_amdgcn_mfma_f32_16x16x32_bf16(va1, pb.s, B0, 0, 0, 0);
        }
        // q-block 1
        {
            float4v s0 = __builtin_amdgcn_mfma_f32_16x16x32_bf16(kf0, qf1, zero, 0, 0, 0);
            float4v s1 = __builtin_amdgcn_mfma_f32_16x16x32_bf16(kf1, qf1, zero, 0, 0, 0);
            union { short8 s; unsigned int u[4]; } pb;
#pragma unroll
            for (int r = 0; r < 4; ++r) {
                float pe = EXP2F(s0[r]), po = EXP2F(s1[r]);
                l1 += pe + po;
                pb.u[r] = pk2bf(pe, po);
            }
            A1 = __builtin_amdgcn_mfma_f32_16x16x32_bf16(va0, pb.s, A1, 0, 0, 0);
            B1 = __builtin_amdgcn_mfma_f32_16x16x32_bf16(va1, pb.s, B1, 0, 0, 0);
        }
    };

    // ---- prologue: stage tiles 0 and 1 ----
#pragma unroll
    for (int p = 0; p < 4; ++p) STAGE1(0, 0, p);
#pragma unroll
    for (int p = 0; p < 4; ++p) STAGE1(1, 1, p);

    int cur = 0;
    for (int t = 0; t < NT; ++t) {
        // tile t resident: outstanding <= tile t+1's 4 loads (t+2 not yet issued)
        if (t + 1 < NT) {
            asm volatile("s_waitcnt vmcnt(4)" ::: "memory");
        } else {
            asm volatile("s_waitcnt vmcnt(0)" ::: "memory");
        }
        __builtin_amdgcn_sched_barrier(0);
        __builtin_amdgcn_s_barrier();   // unions per-wave guarantees; prev iter readers done

        int fut = cur + 2; if (fut >= 3) fut -= 3;
        bool stg = (t + 2 < NT);
        const char* buf = (const char*)lds[cur];

        __builtin_amdgcn_s_setprio(1);
        if (stg) STAGE1(fut, t + 2, 0);
        process(buf,         aA0e, aB0e, aA1e, aB1e);  // keys +0..31
        if (stg) STAGE1(fut, t + 2, 1);
        process(buf + 4096,  aA0o, aB0o, aA1o, aB1o);  // +32..63
        if (stg) STAGE1(fut, t + 2, 2);
        process(buf + 8192,  aA0e, aB0e, aA1e, aB1e);  // +64..95
        if (stg) STAGE1(fut, t + 2, 3);
        process(buf + 12288, aA0o, aB0o, aA1o, aB1o);  // +96..127
        __builtin_amdgcn_s_setprio(0);

        ++cur; if (cur >= 3) cur -= 3;
    }

    // ---- epilogue: merge even/odd; l lane-local per q=r4, sum over g-copies ----
    float4v accA0 = aA0e + aA0o, accB0 = aB0e + aB0o;
    float4v accA1 = aA1e + aA1o, accB1 = aB1e + aB1o;
    l0 += __shfl_xor(l0, 16); l0 += __shfl_xor(l0, 32);
    l1 += __shfl_xor(l1, 16); l1 += __shfl_xor(l1, 32);
    float linv0 = 1.0f / l0, linv1 = 1.0f / l1;

    int b = bh >> 3, h = bh & 7;
    {
        int s = q0 + r4;
        float* op = out + (size_t)(b * NS + s) * ND + h * NDH;
        float4 oa = {accA0[0] * linv0, accA0[1] * linv0, accA0[2] * linv0, accA0[3] * linv0};
        float4 ob = {accB0[0] * linv0, accB0[1] * linv0, accB0[2] * linv0, accB0[3] * linv0};
        *(float4*)(op + 4 * g) = oa;        // dh 4g..4g+3
        *(float4*)(op + 16 + 4 * g) = ob;   // dh 16+4g..19+4g
    }
    {
        int s = q0 + 16 + r4;
        float* op = out + (size_t)(b * NS + s) * ND + h * NDH;
        float4 oa = {accA1[0] * linv1, accA1[1] * linv1, accA1[2] * linv1, accA1[3] * linv1};
        float4 ob = {accB1[0] * linv1, accB1[1] * linv1, accB1[2] * linv1, accB1[3] * linv1};
        *(float4*)(op + 4 * g) = oa;
        *(float4*)(op + 16 + 4 * g) = ob;
    }
#undef STAGE1
}

extern "C" void kernel_launch(void* const* d_in, const int* in_sizes, int n_in,
                              void* d_out, int out_size, void* d_ws, size_t ws_size,
                              hipStream_t stream) {
    const float* seq = (const float*)d_in[0];
    const float* Wq = (const float*)d_in[1];
    const float* Wk = (const float*)d_in[2];
    const float* Wv = (const float*)d_in[3];
    const float* bq = (const float*)d_in[4];
    const float* bk = (const float*)d_in[5];
    const float* bv = (const float*)d_in[6];
    float* out = (float*)d_out;

    // workspace layout (bf16 elements): seqb 2M | Wt 196608 | Q 2M | K 2M | Vt 2M  (~17.2 MB)
    unsigned short* seqb = (unsigned short*)d_ws;
    unsigned short* Wt = seqb + 2097152;
    unsigned short* Qw = Wt + 196608;
    unsigned short* Kw = Qw + 2097152;
    unsigned short* Vtw = Kw + 2097152;

    hipLaunchKernelGGL(prep, dim3(2816), dim3(256), 0, stream, seq, seqb, Wq, Wk, Wv, Wt);
    hipLaunchKernelGGL(proj, dim3(128, 12), dim3(256), 0, stream, seqb, Wt, bq, bk, bv, Qw, Kw, Vtw);
    hipLaunchKernelGGL(attn_kernel, dim3(512), dim3(256), 0, stream, Qw, Kw, Vtw, out);
}

// Round 13
// 58.232 us; speedup vs baseline: 1.0019x; 1.0019x over previous
//
#include <hip/hip_runtime.h>
#include <hip/hip_bf16.h>

// MSA: B=4, S=2048, D=256, H=8, DH=32
// q/k/v = seq @ W[h] + b[h]; out = softmax(q k^T / sqrt(32)) v, heads hstacked -> [B,S,D] f32
//
// attn: 32x32x16 MFMA inner loop -- one wave computes 32q x 32keys per subtile
// with 4 MFMA (2 QK chained over dh + 2 PV over key halves). K rows stored
// sigma-permuted (swap bits 2,3) so the QK accumulator regs [0..7]/[8..15]
// ARE the PV B-fragments (zero shuffles). LDS chunk-swizzled (c^=(row>>1)&3)
// for conflict-free 64B-row reads. 3-buffer counted-vmcnt pipeline (r11's
// proven sync). No max tracking (Q pre-scaled by 1/sqrt(32)*log2e).
// proj: LDS-staged GEMM (r10, proven). prep: fused convert/transpose.

#define NB 4
#define NS 2048
#define ND 256
#define NH 8
#define NDH 32
#define KT 128           // keys per staged macro-tile (4 x 32-key sub-tiles)
#define NT (NS / KT)     // 16 tiles

typedef __attribute__((ext_vector_type(8))) short short8;
typedef __attribute__((ext_vector_type(4))) float float4v;
typedef __attribute__((ext_vector_type(16))) float float16v;

static __device__ __forceinline__ unsigned short f2bf(float f) {
    union { float f; unsigned int u; } v; v.f = f;
    unsigned int r = (v.u + 0x7FFFu + ((v.u >> 16) & 1u)) >> 16;
    return (unsigned short)r;
}

static __device__ __forceinline__ unsigned int pk2bf(float lo, float hi) {
    __hip_bfloat162 h = __float22bfloat162_rn(float2{lo, hi});  // x=lo -> low 16 bits
    union { __hip_bfloat162 h; unsigned int u; } c; c.h = h;
    return c.u;
}

#if defined(__has_builtin)
#if __has_builtin(__builtin_amdgcn_exp2f)
#define EXP2F(x) __builtin_amdgcn_exp2f(x)
#endif
#endif
#ifndef EXP2F
#define EXP2F(x) exp2f(x)
#endif

// ---------------- fused prep: seq f32->bf16 (blocks 0..2047), W transpose (2048..2815) ----------------
__global__ __launch_bounds__(256) void prep(const float* __restrict__ seq,
                                            unsigned short* __restrict__ seqb,
                                            const float* __restrict__ Wq,
                                            const float* __restrict__ Wk,
                                            const float* __restrict__ Wv,
                                            unsigned short* __restrict__ Wt) {
    int bx = (int)blockIdx.x;
    if (bx < 2048) {
        int i = (bx * 256 + (int)threadIdx.x) * 4;  // 2M elems / 4
        float4 v = *(const float4*)(seq + i);
        ushort4 o;
        o.x = f2bf(v.x); o.y = f2bf(v.y); o.z = f2bf(v.z); o.w = f2bf(v.w);
        *(ushort4*)(seqb + i) = o;
    } else {
        int idx = (bx - 2048) * 256 + (int)threadIdx.x;  // 768*256
        int c = idx >> 8, d = idx & 255;
        int mat = c >> 8;
        int cm = c & 255;
        int h = cm >> 5, e = cm & 31;
        const float* W = (mat == 0) ? Wq : (mat == 1) ? Wk : Wv;
        Wt[c * 256 + d] = f2bf(W[(h * 256 + d) * 32 + e]);
    }
}

// ---------------- projection GEMM: M=8192, N=768, K=256, LDS-staged (r10 proven) ----------------
__global__ __launch_bounds__(256, 2) void proj(const unsigned short* __restrict__ seqb,
                                               const unsigned short* __restrict__ Wt,
                                               const float* __restrict__ bq,
                                               const float* __restrict__ bk,
                                               const float* __restrict__ bv,
                                               unsigned short* __restrict__ Q,
                                               unsigned short* __restrict__ K,
                                               unsigned short* __restrict__ Vt) {
    __shared__ __align__(16) unsigned short plds[32768];  // A shorts [0,16384), B [16384,32768)

    int m0 = blockIdx.x * 64;        // 128 m-blocks
    int c0 = blockIdx.y * 64;        // 12 c-blocks (64-col tiles never cross a matrix boundary)
    int tid = (int)threadIdx.x;
    int wave = tid >> 6, lane = tid & 63;
    int g = lane >> 4, r4 = lane & 15;

#pragma unroll
    for (int j = 0; j < 16; ++j) {
        int s = tid + 256 * j;
        int local = s & 2047;
        int row = local >> 5;
        int col16 = (local & 31) ^ (row & 7);
        const unsigned short* src = (s < 2048)
            ? (seqb + (size_t)(m0 + row) * 256 + col16 * 8)
            : (Wt + (size_t)(c0 + row) * 256 + col16 * 8);
        __builtin_amdgcn_global_load_lds(
            (const __attribute__((address_space(1))) unsigned int*)src,
            (__attribute__((address_space(3))) unsigned int*)(&plds[s * 8]), 16, 0, 0);
    }
    __syncthreads();  // drains vmcnt(0): both tiles resident

    const unsigned short* ldsA = plds;
    const unsigned short* ldsB = plds + 16384;
    int rowA = wave * 16 + r4;
    int xA = r4 & 7;

    float4v acc[4];
#pragma unroll
    for (int ct = 0; ct < 4; ++ct) acc[ct] = (float4v){0.f, 0.f, 0.f, 0.f};

#pragma unroll
    for (int i = 0; i < 8; ++i) {
        int cp = ((4 * i + g) ^ xA) * 8;
        short8 a = *(const short8*)(ldsA + rowA * 256 + cp);
#pragma unroll
        for (int ct = 0; ct < 4; ++ct) {
            short8 b = *(const short8*)(ldsB + (ct * 16 + r4) * 256 + cp);
            acc[ct] = __builtin_amdgcn_mfma_f32_16x16x32_bf16(a, b, acc[ct], 0, 0, 0);
        }
    }

    const float SC = 0.17677669529663687f * 1.4426950408889634f;  // 1/sqrt(32)*log2(e)
#pragma unroll
    for (int ct = 0; ct < 4; ++ct) {
        int c = c0 + ct * 16 + r4;
        int mat = c >> 8;
        int cm = c & 255;
        int h = cm >> 5, e = cm & 31;
        float bias = ((mat == 0) ? bq : (mat == 1) ? bk : bv)[cm];
#pragma unroll
        for (int r = 0; r < 4; ++r) {
            int m = m0 + wave * 16 + 4 * g + r;
            int b = m >> 11, s = m & 2047;
            float val = acc[ct][r] + bias;
            if (mat == 0) {
                Q[((b * NH + h) * NS + s) * NDH + e] = f2bf(val * SC);
            } else if (mat == 1) {
                K[((b * NH + h) * NS + s) * NDH + e] = f2bf(val);
            } else {
                Vt[((b * NH + h) * NDH + e) * NS + s] = f2bf(val);
            }
        }
    }
}

// ---------------- flash attention, 32x32x16 MFMA, 3-buffer counted-vmcnt ----------------
// grid: 512 blocks (32 bh x 16 q-tiles of 128), XCD-swizzled. block: 4 waves.
// Wave owns 32 q-rows (one 32x32 output). 128-key macro tiles (4 x 32-key
// sub-tiles), triple-buffered (3 x 16KB). Each 4KB sub-tile:
//   K 2KB: QK-A row i (64B: 32 dh) holds physical key sigma(i), sigma = swap
//          bits 2,3 of i; 16B chunks stored at c' = c ^ ((i>>1)&3).
//   V 2KB: row dh (64B: 32 keys), chunks swizzled the same way.
// QK D-layout (verified m74/m101): col=lane&31 (q), row=(r&3)+8(r>>2)+4*(lane>>5)
// (permuted key) => acc regs [0..7] = PV1 B-frag, [8..15] = PV2 B-frag.
__global__ __launch_bounds__(256, 2) void attn_kernel(const unsigned short* __restrict__ Q,
                                                      const unsigned short* __restrict__ K,
                                                      const unsigned short* __restrict__ Vt,
                                                      float* __restrict__ out) {
    __shared__ __align__(16) unsigned short lds[3][8192];  // 3 x 16KB

    int bx = (int)blockIdx.x;
    int wid = (bx & 7) * 64 + (bx >> 3);   // XCD swizzle (512 % 8 == 0)
    int bh = wid >> 4;
    int qt = wid & 15;
    int tid = (int)threadIdx.x;
    int wave = tid >> 6, lane = tid & 63;
    int r31 = lane & 31, hi2 = lane >> 5;
    int q0 = qt * 128 + wave * 32;

    const unsigned short* Qb = Q + (size_t)bh * NS * NDH;
    const unsigned short* Kb = K + (size_t)bh * NS * NDH;
    const unsigned short* Vb = Vt + (size_t)bh * NDH * NS;

    // ---- staging: thread stages one 16B slot per 32-key sub-tile (4/macro) ----
    // slot s = row*4 + c_store (row = s>>2, 64B rows). Stored chunk c_store holds
    // source chunk c = c_store ^ ((row>>1)&3). K row holds key sigma(row).
    const unsigned short* sgp;
    int strideT;         // shorts per 128-key macro-tile
    int strideB;         // shorts per 32-key sub-tile step
    unsigned int sloff;  // dest offset within a buffer, in shorts
    {
        int s = tid & 127;
        int row = s >> 2;
        int srcC = (s & 3) ^ ((row >> 1) & 3);
        if (tid < 128) {  // K region
            int key = (row & ~12) | ((row & 4) << 1) | ((row & 8) >> 1);  // swap bits 2,3
            sgp = Kb + key * NDH + srcC * 8;
            strideT = KT * NDH;   // 4096
            strideB = 32 * NDH;   // 1024
            sloff = s * 8;
        } else {          // V region: row = dh
            sgp = Vb + row * NS + srcC * 8;
            strideT = KT;         // 128
            strideB = 32;
            sloff = 1024 + s * 8;
        }
    }

#define STAGE(bufi, t)                                                                        \
    do {                                                                                      \
        const unsigned short* _s = sgp + (size_t)(t) * strideT;                               \
        __builtin_amdgcn_global_load_lds(                                                     \
            (const __attribute__((address_space(1))) unsigned int*)(_s),                      \
            (__attribute__((address_space(3))) unsigned int*)(&lds[bufi][sloff]), 16, 0, 0);  \
        __builtin_amdgcn_global_load_lds(                                                     \
            (const __attribute__((address_space(1))) unsigned int*)(_s + strideB),            \
            (__attribute__((address_space(3))) unsigned int*)(&lds[bufi][sloff + 2048]), 16, 0, 0); \
        __builtin_amdgcn_global_load_lds(                                                     \
            (const __attribute__((address_space(1))) unsigned int*)(_s + 2 * strideB),        \
            (__attribute__((address_space(3))) unsigned int*)(&lds[bufi][sloff + 4096]), 16, 0, 0); \
        __builtin_amdgcn_global_load_lds(                                                     \
            (const __attribute__((address_space(1))) unsigned int*)(_s + 3 * strideB),        \
            (__attribute__((address_space(3))) unsigned int*)(&lds[bufi][sloff + 6144]), 16, 0, 0); \
    } while (0)

    // ---- per-lane read offsets (bytes within a 4KB sub-tile) ----
    int rx = (r31 >> 1) & 3;
    int kOffA = r31 * 64 + ((hi2 ^ rx) << 4);              // K, dh chunk hi2 (dh 8*hi2..)
    int kOffB = r31 * 64 + (((2 + hi2) ^ rx) << 4);        // K, dh chunk 2+hi2 (dh 16+8*hi2..)
    int vOffA = 2048 + r31 * 64 + ((hi2 ^ rx) << 4);       // V, key chunk hi2 (PV1)
    int vOffB = 2048 + r31 * 64 + (((2 + hi2) ^ rx) << 4); // V, key chunk 2+hi2 (PV2)

    // ---- Q fragments (B operand of QK): col q = r31, k = dh 8*hi2+j (+16) ----
    const unsigned short* qrow = Qb + (q0 + r31) * NDH;
    short8 qa = *(const short8*)(qrow + 8 * hi2);
    short8 qb = *(const short8*)(qrow + 16 + 8 * hi2);

    float16v accE = {0.f}, accO = {0.f};
    const float16v zero16 = {0.f};
    float lp = 0.f;

    auto process = [&](const char* buf, float16v& acc) {
        short8 kfA = *(const short8*)(buf + kOffA);
        short8 kfB = *(const short8*)(buf + kOffB);
        short8 vfA = *(const short8*)(buf + vOffA);
        short8 vfB = *(const short8*)(buf + vOffB);
        // QK: D[perm key][q], chained over dh halves
        float16v s = __builtin_amdgcn_mfma_f32_32x32x16_bf16(kfA, qa, zero16, 0, 0, 0);
        s = __builtin_amdgcn_mfma_f32_32x32x16_bf16(kfB, qb, s, 0, 0, 0);
        float p[16];
#pragma unroll
        for (int r = 0; r < 16; ++r) p[r] = EXP2F(s[r]);
#pragma unroll
        for (int r = 0; r < 16; ++r) lp += p[r];
        union { short8 v; unsigned int u[4]; } pb1, pb2;
#pragma unroll
        for (int w = 0; w < 4; ++w) {
            pb1.u[w] = pk2bf(p[2 * w], p[2 * w + 1]);          // regs 0..7  -> PV1 k-slots
            pb2.u[w] = pk2bf(p[8 + 2 * w], p[9 + 2 * w]);      // regs 8..15 -> PV2 k-slots
        }
        // PV: A = V (dh x keys), B = P (keys x q); two key-halves accumulate
        acc = __builtin_amdgcn_mfma_f32_32x32x16_bf16(vfA, pb1.v, acc, 0, 0, 0);
        acc = __builtin_amdgcn_mfma_f32_32x32x16_bf16(vfB, pb2.v, acc, 0, 0, 0);
    };

    // ---- prologue: stage tiles 0 and 1 ----
    STAGE(0, 0);
    STAGE(1, 1);

    int cur = 0;
    for (int t = 0; t < NT; ++t) {
        __builtin_amdgcn_s_barrier();   // prev-iter readers of buf[(t+2)%3] done
        if (t + 2 < NT) {
            int fut = cur + 2; if (fut >= 3) fut -= 3;
            STAGE(fut, t + 2);
            // outstanding: tiles t,t+1,t+2 (12 loads); drain to 8 -> tile t resident
            asm volatile("s_waitcnt vmcnt(8)" ::: "memory");
        } else if (t + 1 < NT) {
            asm volatile("s_waitcnt vmcnt(4)" ::: "memory");
        } else {
            asm volatile("s_waitcnt vmcnt(0)" ::: "memory");
        }
        __builtin_amdgcn_sched_barrier(0);

        __builtin_amdgcn_s_setprio(1);
        const char* buf = (const char*)lds[cur];
        process(buf, accE);            // keys +0..31
        process(buf + 4096, accO);     // +32..63
        process(buf + 8192, accE);     // +64..95
        process(buf + 12288, accO);    // +96..127
        __builtin_amdgcn_s_setprio(0);

        __builtin_amdgcn_sched_barrier(0);
        ++cur; if (cur >= 3) cur -= 3;
    }

    // ---- epilogue: l per q = lane + partner (lane^32); store 4 dh-quads ----
    lp += __shfl_xor(lp, 32);
    float linv = 1.0f / lp;
    float16v accT = accE + accO;

    int b = bh >> 3, h = bh & 7;
    int srow = q0 + r31;
    float* op = out + (size_t)(b * NS + srow) * ND + h * NDH + 4 * hi2;
#pragma unroll
    for (int i = 0; i < 4; ++i) {
        // acc regs 4i..4i+3 hold dh = {0..3} + 8*i + 4*hi2
        float4 o4 = {accT[4 * i] * linv, accT[4 * i + 1] * linv,
                     accT[4 * i + 2] * linv, accT[4 * i + 3] * linv};
        *(float4*)(op + 8 * i) = o4;
    }
#undef STAGE
}

extern "C" void kernel_launch(void* const* d_in, const int* in_sizes, int n_in,
                              void* d_out, int out_size, void* d_ws, size_t ws_size,
                              hipStream_t stream) {
    const float* seq = (const float*)d_in[0];
    const float* Wq = (const float*)d_in[1];
    const float* Wk = (const float*)d_in[2];
    const float* Wv = (const float*)d_in[3];
    const float* bq = (const float*)d_in[4];
    const float* bk = (const float*)d_in[5];
    const float* bv = (const float*)d_in[6];
    float* out = (float*)d_out;

    // workspace layout (bf16 elements): seqb 2M | Wt 196608 | Q 2M | K 2M | Vt 2M  (~17.2 MB)
    unsigned short* seqb = (unsigned short*)d_ws;
    unsigned short* Wt = seqb + 2097152;
    unsigned short* Qw = Wt + 196608;
    unsigned short* Kw = Qw + 2097152;
    unsigned short* Vtw = Kw + 2097152;

    hipLaunchKernelGGL(prep, dim3(2816), dim3(256), 0, stream, seq, seqb, Wq, Wk, Wv, Wt);
    hipLaunchKernelGGL(proj, dim3(128, 12), dim3(256), 0, stream, seqb, Wt, bq, bk, bv, Qw, Kw, Vtw);
    hipLaunchKernelGGL(attn_kernel, dim3(512), dim3(256), 0, stream, Qw, Kw, Vtw, out);
}